// Round 2
// baseline (218.734 us; speedup 1.0000x reference)
//
#include <hip/hip_runtime.h>

// FeatureFinetuningLoss: total = (1/C) * sum_{b,c} max(|m_bc - pos_c + eps| - |m_bc - neg_c + eps| + 1, 0)
// m_bc = mean over 196 spatial elems of (qual[b]==1 ? feat : feat_p)[b,c,:,:]
// pos_c = avg_feat[label[b]][c], neg_c = avg_feat[1-label[b]][c]
//
// R2: thread-per-channel streaming. One thread = one channel = 49 independent
// float4 loads (all 64 lanes active, no shuffles in the hot loop). Only the
// SELECTED tensor per sample is read (~103 MB of the 205 MB total).

#define B_ 128
#define C_ 1024
#define HW_ 196
#define NF4_ 49                    // float4s per channel (784 B)
#define TPB_ 256
#define NBLOCKS_ (B_ * C_ / TPB_)  // 512 blocks, 2/CU

__global__ __launch_bounds__(TPB_) void loss_partial_kernel(
    const float* __restrict__ feat, const float* __restrict__ feat_p,
    const float* __restrict__ af, const int* __restrict__ qual,
    const int* __restrict__ label, float* __restrict__ ws)
{
    const int blk = blockIdx.x;
    const int b   = blk >> 2;                       // 4 blocks per sample
    const int c   = ((blk & 3) << 8) | threadIdx.x; // this thread's channel

    const int q   = qual[b];                        // block-uniform -> scalar
    const int lab = label[b];
    const float* sel = (q == 1 ? feat : feat_p);
    const float4* p = (const float4*)(sel + ((size_t)b * C_ + c) * HW_);

    // 49 independent 16B loads; 4 accumulator chains to keep adds off the
    // critical path while loads stream.
    float s0 = 0.f, s1 = 0.f, s2 = 0.f, s3 = 0.f;
    #pragma unroll
    for (int i = 0; i < NF4_; ++i) {
        float4 v = p[i];
        s0 += v.x; s1 += v.y; s2 += v.z; s3 += v.w;
    }
    const float mean = ((s0 + s1) + (s2 + s3)) * (1.0f / 196.0f);

    const float pos = af[lab * C_ + c];             // coalesced 1KB row
    const float neg = af[(1 - lab) * C_ + c];
    const float dap = fabsf(mean - pos + 1e-6f);
    const float dan = fabsf(mean - neg + 1e-6f);
    float h = fmaxf(dap - dan + 1.0f, 0.0f);

    // block reduction: 64-lane butterfly, then LDS across 4 waves
    #pragma unroll
    for (int off = 32; off > 0; off >>= 1)
        h += __shfl_xor(h, off, 64);
    __shared__ float sred[TPB_ / 64];
    const int wave = threadIdx.x >> 6;
    if ((threadIdx.x & 63) == 0) sred[wave] = h;
    __syncthreads();
    if (threadIdx.x == 0)
        ws[blk] = (sred[0] + sred[1]) + (sred[2] + sred[3]);
}

__global__ __launch_bounds__(TPB_) void final_reduce_kernel(
    const float* __restrict__ ws, float* __restrict__ out)
{
    const int tid = threadIdx.x;
    float s = ws[tid] + ws[tid + TPB_];             // NBLOCKS_ = 2*TPB_
    #pragma unroll
    for (int off = 32; off > 0; off >>= 1)
        s += __shfl_xor(s, off, 64);
    __shared__ float sred[TPB_ / 64];
    if ((tid & 63) == 0) sred[tid >> 6] = s;
    __syncthreads();
    if (tid == 0)
        out[0] = ((sred[0] + sred[1]) + (sred[2] + sred[3])) * (1.0f / (float)C_);
}

extern "C" void kernel_launch(void* const* d_in, const int* in_sizes, int n_in,
                              void* d_out, int out_size, void* d_ws, size_t ws_size,
                              hipStream_t stream) {
    const float* feat   = (const float*)d_in[0];
    const float* feat_p = (const float*)d_in[1];
    const float* af     = (const float*)d_in[2];   // (2, C)
    const int*   qual   = (const int*)d_in[3];
    const int*   label  = (const int*)d_in[4];
    float* out = (float*)d_out;
    float* ws  = (float*)d_ws;                     // NBLOCKS_ floats = 2 KB

    loss_partial_kernel<<<NBLOCKS_, TPB_, 0, stream>>>(feat, feat_p, af, qual, label, ws);
    final_reduce_kernel<<<1, TPB_, 0, stream>>>(ws, out);
}

// Round 3
// 200.517 us; speedup vs baseline: 1.0909x; 1.0909x over previous
//
#include <hip/hip_runtime.h>

// FeatureFinetuningLoss: total = (1/C) * sum_{b,c} max(|m_bc - pos_c + eps| - |m_bc - neg_c + eps| + 1, 0)
// m_bc = mean over 196 spatial elems of (qual[b]==1 ? feat : feat_p)[b,c,:,:]
//
// R3: wave-per-channel (lanes 0..48 each load one float4 of the 784B channel
// -> 7 cache lines per load instruction, fully coalesced). 16 channels per
// wave issued back-to-back for MLP. R2's thread-per-channel was TA-bound
// (784B lane stride = 64 lines per instruction, 946 GB/s); this restores
// coalescing. Only the SELECTED tensor per sample is read (~103 MB logical).

#define B_ 128
#define C_ 1024
#define HW_ 196
#define NF4_ 49                     // float4s per channel (784 B)
#define CPW_ 16                     // channels per wave
#define WPB_ 4                      // waves per block
#define CPB_ (CPW_ * WPB_)          // 64 channels per block
#define BLKS_PER_B_ (C_ / CPB_)     // 16
#define NBLOCKS_ (B_ * BLKS_PER_B_) // 2048 -> 8 blocks/CU, full occupancy
#define TPB_ 256

__global__ __launch_bounds__(TPB_) void loss_partial_kernel(
    const float* __restrict__ feat, const float* __restrict__ feat_p,
    const float* __restrict__ af, const int* __restrict__ qual,
    const int* __restrict__ label, float* __restrict__ ws)
{
    const int blk  = blockIdx.x;
    const int b    = blk >> 4;                 // 16 blocks per sample
    const int cg   = blk & 15;
    const int wave = threadIdx.x >> 6;
    const int lane = threadIdx.x & 63;
    const int c0   = (cg << 6) | (wave << 4);  // first channel of this wave

    const int q   = qual[b];                   // block-uniform -> scalar
    const int lab = label[b];
    const float* sel  = (q == 1 ? feat : feat_p);
    const float* base = sel + ((size_t)b * C_ + c0) * HW_;
    const float* pos_row = af + (size_t)lab * C_;
    const float* neg_row = af + (size_t)(1 - lab) * C_;

    // 16 coalesced 784B channel loads, all issued before first use.
    const bool act = (lane < NF4_);
    float4 v[CPW_];
    #pragma unroll
    for (int j = 0; j < CPW_; ++j) {
        float4 t = make_float4(0.f, 0.f, 0.f, 0.f);
        if (act) t = ((const float4*)(base + j * HW_))[lane];
        v[j] = t;
    }

    float hacc = 0.0f;
    #pragma unroll
    for (int j = 0; j < CPW_; ++j) {
        float s = (v[j].x + v[j].y) + (v[j].z + v[j].w);
        #pragma unroll
        for (int off = 32; off > 0; off >>= 1)
            s += __shfl_xor(s, off, 64);
        const float mean = s * (1.0f / 196.0f);
        const int c = c0 + j;
        const float dap = fabsf(mean - pos_row[c] + 1e-6f);
        const float dan = fabsf(mean - neg_row[c] + 1e-6f);
        hacc += fmaxf(dap - dan + 1.0f, 0.0f);
    }

    __shared__ float sred[WPB_];
    if (lane == 0) sred[wave] = hacc;
    __syncthreads();
    if (threadIdx.x == 0)
        ws[blk] = (sred[0] + sred[1]) + (sred[2] + sred[3]);
}

__global__ __launch_bounds__(TPB_) void final_reduce_kernel(
    const float* __restrict__ ws, float* __restrict__ out)
{
    const int tid = threadIdx.x;
    float s = 0.0f;
    #pragma unroll
    for (int i = 0; i < NBLOCKS_ / TPB_; ++i)   // 8 loads
        s += ws[tid + i * TPB_];
    #pragma unroll
    for (int off = 32; off > 0; off >>= 1)
        s += __shfl_xor(s, off, 64);
    __shared__ float sred[TPB_ / 64];
    if ((tid & 63) == 0) sred[tid >> 6] = s;
    __syncthreads();
    if (tid == 0)
        out[0] = ((sred[0] + sred[1]) + (sred[2] + sred[3])) * (1.0f / (float)C_);
}

extern "C" void kernel_launch(void* const* d_in, const int* in_sizes, int n_in,
                              void* d_out, int out_size, void* d_ws, size_t ws_size,
                              hipStream_t stream) {
    const float* feat   = (const float*)d_in[0];
    const float* feat_p = (const float*)d_in[1];
    const float* af     = (const float*)d_in[2];   // (2, C)
    const int*   qual   = (const int*)d_in[3];
    const int*   label  = (const int*)d_in[4];
    float* out = (float*)d_out;
    float* ws  = (float*)d_ws;                     // NBLOCKS_ floats = 8 KB

    loss_partial_kernel<<<NBLOCKS_, TPB_, 0, stream>>>(feat, feat_p, af, qual, label, ws);
    final_reduce_kernel<<<1, TPB_, 0, stream>>>(ws, out);
}

// Round 4
// 199.895 us; speedup vs baseline: 1.0942x; 1.0031x over previous
//
#include <hip/hip_runtime.h>

// FeatureFinetuningLoss: total = (1/C) * sum_{b,c} max(|m_bc - pos_c + eps| - |m_bc - neg_c + eps| + 1, 0)
// m_bc = mean over 196 spatial elems of (qual[b]==1 ? feat : feat_p)[b,c,:,:]
//
// R4: wave-per-64-channels. 64 ch x 49 float4 = 3136 f4 = 49 FULL-wave
// coalesced float4 loads (no predication, no hot-loop shuffles). Each lane
// reduces its float4 to a scalar into LDS at the flat f4 index; then lane l
// sums channel l's 49 partials (stride 49 words: odd -> conflict-free) and
// computes the hinge. One butterfly per block. Single-wave blocks, no barrier
// pressure. Only the SELECTED tensor per sample is read (~103 MB logical).

#define B_ 128
#define C_ 1024
#define HW_ 196
#define NF4_ 49                       // float4s per channel (784 B)
#define CPB_ 64                       // channels per block (one wave)
#define NBLOCKS_ (B_ * C_ / CPB_)     // 2048 -> 8 waves/CU
#define LDSN_ (CPB_ * NF4_)           // 3136 floats = 12.25 KB

__global__ __launch_bounds__(64) void loss_partial_kernel(
    const float* __restrict__ feat, const float* __restrict__ feat_p,
    const float* __restrict__ af, const int* __restrict__ qual,
    const int* __restrict__ label, float* __restrict__ ws)
{
    __shared__ float lsum[LDSN_];
    const int blk  = blockIdx.x;
    const int b    = blk >> 4;             // 16 blocks per sample
    const int cg   = blk & 15;
    const int lane = threadIdx.x;          // 0..63
    const int c0   = cg << 6;

    const int q   = qual[b];               // block-uniform -> scalar
    const int lab = label[b];
    const float* sel = (q == 1 ? feat : feat_p);
    const float4* base = (const float4*)(sel + ((size_t)b * C_ + c0) * HW_);

    // Phase 1: 49 full-wave float4 loads in 7 chunks of 7 (7 KB in flight).
    #pragma unroll
    for (int chunk = 0; chunk < 7; ++chunk) {
        float4 t[7];
        #pragma unroll
        for (int k = 0; k < 7; ++k)
            t[k] = base[(chunk * 7 + k) * 64 + lane];
        #pragma unroll
        for (int k = 0; k < 7; ++k)
            lsum[(chunk * 7 + k) * 64 + lane] =
                (t[k].x + t[k].y) + (t[k].z + t[k].w);
    }
    __syncthreads();                       // single wave: just drains lgkmcnt

    // Phase 2: lane l sums channel l's 49 partials (stride 49 = odd -> no conflicts).
    const float* my = &lsum[lane * NF4_];
    float a0 = 0.f, a1 = 0.f, a2 = 0.f, a3 = 0.f;
    #pragma unroll
    for (int j = 0; j < 48; j += 4) {
        a0 += my[j]; a1 += my[j + 1]; a2 += my[j + 2]; a3 += my[j + 3];
    }
    const float s = ((a0 + a1) + (a2 + a3)) + my[48];
    const float mean = s * (1.0f / 196.0f);

    const int c = c0 + lane;
    const float pos = af[lab * C_ + c];
    const float neg = af[(1 - lab) * C_ + c];
    float h = fmaxf(fabsf(mean - pos + 1e-6f) - fabsf(mean - neg + 1e-6f) + 1.0f, 0.0f);

    #pragma unroll
    for (int off = 32; off > 0; off >>= 1)
        h += __shfl_xor(h, off, 64);
    if (lane == 0) ws[blk] = h;
}

__global__ __launch_bounds__(256) void final_reduce_kernel(
    const float* __restrict__ ws, float* __restrict__ out)
{
    const int tid = threadIdx.x;
    float s = 0.0f;
    #pragma unroll
    for (int i = 0; i < NBLOCKS_ / 256; ++i)   // 8 loads
        s += ws[tid + i * 256];
    #pragma unroll
    for (int off = 32; off > 0; off >>= 1)
        s += __shfl_xor(s, off, 64);
    __shared__ float sred[4];
    if ((tid & 63) == 0) sred[tid >> 6] = s;
    __syncthreads();
    if (tid == 0)
        out[0] = ((sred[0] + sred[1]) + (sred[2] + sred[3])) * (1.0f / (float)C_);
}

extern "C" void kernel_launch(void* const* d_in, const int* in_sizes, int n_in,
                              void* d_out, int out_size, void* d_ws, size_t ws_size,
                              hipStream_t stream) {
    const float* feat   = (const float*)d_in[0];
    const float* feat_p = (const float*)d_in[1];
    const float* af     = (const float*)d_in[2];   // (2, C)
    const int*   qual   = (const int*)d_in[3];
    const int*   label  = (const int*)d_in[4];
    float* out = (float*)d_out;
    float* ws  = (float*)d_ws;                     // NBLOCKS_ floats = 8 KB

    loss_partial_kernel<<<NBLOCKS_, 64, 0, stream>>>(feat, feat_p, af, qual, label, ws);
    final_reduce_kernel<<<1, 256, 0, stream>>>(ws, out);
}

// Round 5
// 198.341 us; speedup vs baseline: 1.1028x; 1.0078x over previous
//
#include <hip/hip_runtime.h>

// FeatureFinetuningLoss: total = (1/C) * sum_{b,c} max(|m_bc - pos_c + eps| - |m_bc - neg_c + eps| + 1, 0)
// m_bc = mean over 196 spatial elems of (qual[b]==1 ? feat : feat_p)[b,c,:,:]
//
// R5: latency attack on the R4 flat-load scheme.
//  - 32 channels/block (64-thr single-wave blocks), 4096 blocks
//    -> 16 blocks/CU = 4 waves/SIMD (2x R4's residency).
//  - 49 f4-loads per 32 channels = 24 full-wave + 1 half-wave load, issued in
//    bursts of 13/12 before any use (13 KB in flight per wave; ~200 KB/CU).
//  - LDS transpose: flat f4-sums in, per-channel reads out (stride 49 words,
//    <=2-way bank aliasing = free). Lane pair (l, l+32) splits channel l&31.
// Only the SELECTED tensor per sample is read (~103 MB logical).

#define B_ 128
#define C_ 1024
#define HW_ 196
#define NF4_ 49                       // float4s per channel (784 B)
#define CPB_ 32                       // channels per block
#define NF4B_ (CPB_ * NF4_)           // 1568 f4-sums per block
#define NBLOCKS_ (B_ * C_ / CPB_)     // 4096 -> 16 blocks/CU

__global__ __launch_bounds__(64, 4) void loss_partial_kernel(
    const float* __restrict__ feat, const float* __restrict__ feat_p,
    const float* __restrict__ af, const int* __restrict__ qual,
    const int* __restrict__ label, float* __restrict__ ws)
{
    __shared__ float lsum[NF4B_];          // 6.27 KB
    const int blk  = blockIdx.x;
    const int b    = blk >> 5;             // 32 blocks per sample
    const int c0   = (blk & 31) << 5;      // first channel of this block
    const int lane = threadIdx.x;          // 0..63

    const int q   = qual[b];               // block-uniform -> scalar
    const int lab = label[b];
    const float* sel = (q == 1 ? feat : feat_p);
    const float4* base = (const float4*)(sel + ((size_t)b * C_ + c0) * HW_);

    // ---- Phase 1: 24 full-wave float4 loads + 1 half-wave, in two bursts ----
    {   // burst A: loads 0..12 (13 KB in flight)
        float4 t[13];
        #pragma unroll
        for (int i = 0; i < 13; ++i) t[i] = base[i * 64 + lane];
        #pragma unroll
        for (int i = 0; i < 13; ++i)
            lsum[i * 64 + lane] = (t[i].x + t[i].y) + (t[i].z + t[i].w);
    }
    {   // burst B: loads 13..23 + half-load 24 (lanes 0..31)
        float4 t[11];
        #pragma unroll
        for (int i = 0; i < 11; ++i) t[i] = base[(13 + i) * 64 + lane];
        float4 u = make_float4(0.f, 0.f, 0.f, 0.f);
        if (lane < 32) u = base[24 * 64 + lane];
        #pragma unroll
        for (int i = 0; i < 11; ++i)
            lsum[(13 + i) * 64 + lane] = (t[i].x + t[i].y) + (t[i].z + t[i].w);
        if (lane < 32)
            lsum[24 * 64 + lane] = (u.x + u.y) + (u.z + u.w);
    }
    __syncthreads();

    // ---- Phase 2: lane pair (ch, ch+32) sums channel ch's 49 partials ----
    const int ch   = lane & 31;
    const int half = lane >> 5;
    const float* my = &lsum[ch * NF4_];
    const int start = half * 24;           // half0: j 0..23, half1: j 24..48
    float a0 = 0.f, a1 = 0.f;
    #pragma unroll
    for (int j = 0; j < 24; j += 2) {
        a0 += my[start + j];
        a1 += my[start + j + 1];
    }
    if (half) a0 += my[48];
    float s = a0 + a1;
    s += __shfl_xor(s, 32, 64);            // full channel sum in both halves
    const float mean = s * (1.0f / 196.0f);

    const int c = c0 + ch;
    const float pos = af[lab * C_ + c];
    const float neg = af[(1 - lab) * C_ + c];
    float h = fmaxf(fabsf(mean - pos + 1e-6f) - fabsf(mean - neg + 1e-6f) + 1.0f, 0.0f);

    // reduce 32 channel-hinges (each 32-half holds all 32 channels once)
    #pragma unroll
    for (int off = 16; off > 0; off >>= 1)
        h += __shfl_xor(h, off, 64);
    if (lane == 0) ws[blk] = h;
}

__global__ __launch_bounds__(256) void final_reduce_kernel(
    const float* __restrict__ ws, float* __restrict__ out)
{
    const int tid = threadIdx.x;
    float s = 0.0f;
    #pragma unroll
    for (int i = 0; i < NBLOCKS_ / 256; ++i)   // 16 loads
        s += ws[tid + i * 256];
    #pragma unroll
    for (int off = 32; off > 0; off >>= 1)
        s += __shfl_xor(s, off, 64);
    __shared__ float sred[4];
    if ((tid & 63) == 0) sred[tid >> 6] = s;
    __syncthreads();
    if (tid == 0)
        out[0] = ((sred[0] + sred[1]) + (sred[2] + sred[3])) * (1.0f / (float)C_);
}

extern "C" void kernel_launch(void* const* d_in, const int* in_sizes, int n_in,
                              void* d_out, int out_size, void* d_ws, size_t ws_size,
                              hipStream_t stream) {
    const float* feat   = (const float*)d_in[0];
    const float* feat_p = (const float*)d_in[1];
    const float* af     = (const float*)d_in[2];   // (2, C)
    const int*   qual   = (const int*)d_in[3];
    const int*   label  = (const int*)d_in[4];
    float* out = (float*)d_out;
    float* ws  = (float*)d_ws;                     // NBLOCKS_ floats = 16 KB

    loss_partial_kernel<<<NBLOCKS_, 64, 0, stream>>>(feat, feat_p, af, qual, label, ws);
    final_reduce_kernel<<<1, 256, 0, stream>>>(ws, out);
}

// Round 6
// 185.614 us; speedup vs baseline: 1.1784x; 1.0686x over previous
//
#include <hip/hip_runtime.h>

// FeatureFinetuningLoss: total = (1/C) * sum_{b,c} max(|m_bc - pos_c + eps| - |m_bc - neg_c + eps| + 1, 0)
// m_bc = mean over 196 spatial elems of (qual[b]==1 ? feat : feat_p)[b,c,:,:]
//
// R6: R5 structure + NON-TEMPORAL loads for the stream-once channel data.
// Theory: harness writes ~600 MB (ws poison + d_in restore) right before each
// timed launch, leaving L2/L3 full; normal loads allocate on miss and churn
// those lines out (eviction/writeback competing with our reads -> observed
// 2.5 TB/s effective across ALL kernel shapes R1-R5). nt loads skip
// allocation; reads should run at HBM read rate. Everything else identical
// to R5 so the delta is attributable to nt.

#define B_ 128
#define C_ 1024
#define HW_ 196
#define NF4_ 49                       // float4s per channel (784 B)
#define CPB_ 32                       // channels per block
#define NF4B_ (CPB_ * NF4_)           // 1568 f4-sums per block
#define NBLOCKS_ (B_ * C_ / CPB_)     // 4096 -> 16 blocks/CU

typedef float v4f __attribute__((ext_vector_type(4)));

__global__ __launch_bounds__(64, 4) void loss_partial_kernel(
    const float* __restrict__ feat, const float* __restrict__ feat_p,
    const float* __restrict__ af, const int* __restrict__ qual,
    const int* __restrict__ label, float* __restrict__ ws)
{
    __shared__ float lsum[NF4B_];          // 6.27 KB
    const int blk  = blockIdx.x;
    const int b    = blk >> 5;             // 32 blocks per sample
    const int c0   = (blk & 31) << 5;      // first channel of this block
    const int lane = threadIdx.x;          // 0..63

    const int q   = qual[b];               // block-uniform -> scalar
    const int lab = label[b];
    const float* sel = (q == 1 ? feat : feat_p);
    const v4f* base = (const v4f*)(sel + ((size_t)b * C_ + c0) * HW_);

    // ---- Phase 1: 24 full-wave nt float4 loads + 1 half-wave, two bursts ----
    {   // burst A: loads 0..12 (13 KB in flight)
        v4f t[13];
        #pragma unroll
        for (int i = 0; i < 13; ++i)
            t[i] = __builtin_nontemporal_load(&base[i * 64 + lane]);
        #pragma unroll
        for (int i = 0; i < 13; ++i)
            lsum[i * 64 + lane] = (t[i].x + t[i].y) + (t[i].z + t[i].w);
    }
    {   // burst B: loads 13..23 + half-load 24 (lanes 0..31)
        v4f t[11];
        #pragma unroll
        for (int i = 0; i < 11; ++i)
            t[i] = __builtin_nontemporal_load(&base[(13 + i) * 64 + lane]);
        v4f u = (v4f)(0.f);
        if (lane < 32) u = __builtin_nontemporal_load(&base[24 * 64 + lane]);
        #pragma unroll
        for (int i = 0; i < 11; ++i)
            lsum[(13 + i) * 64 + lane] = (t[i].x + t[i].y) + (t[i].z + t[i].w);
        if (lane < 32)
            lsum[24 * 64 + lane] = (u.x + u.y) + (u.z + u.w);
    }
    __syncthreads();

    // ---- Phase 2: lane pair (ch, ch+32) sums channel ch's 49 partials ----
    const int ch   = lane & 31;
    const int half = lane >> 5;
    const float* my = &lsum[ch * NF4_];
    const int start = half * 24;           // half0: j 0..23, half1: j 24..48
    float a0 = 0.f, a1 = 0.f;
    #pragma unroll
    for (int j = 0; j < 24; j += 2) {
        a0 += my[start + j];
        a1 += my[start + j + 1];
    }
    if (half) a0 += my[48];
    float s = a0 + a1;
    s += __shfl_xor(s, 32, 64);            // full channel sum in both halves
    const float mean = s * (1.0f / 196.0f);

    const int c = c0 + ch;
    const float pos = af[lab * C_ + c];
    const float neg = af[(1 - lab) * C_ + c];
    float h = fmaxf(fabsf(mean - pos + 1e-6f) - fabsf(mean - neg + 1e-6f) + 1.0f, 0.0f);

    // reduce 32 channel-hinges (each 32-half holds all 32 channels once)
    #pragma unroll
    for (int off = 16; off > 0; off >>= 1)
        h += __shfl_xor(h, off, 64);
    if (lane == 0) ws[blk] = h;
}

__global__ __launch_bounds__(256) void final_reduce_kernel(
    const float* __restrict__ ws, float* __restrict__ out)
{
    const int tid = threadIdx.x;
    float s = 0.0f;
    #pragma unroll
    for (int i = 0; i < NBLOCKS_ / 256; ++i)   // 16 loads
        s += ws[tid + i * 256];
    #pragma unroll
    for (int off = 32; off > 0; off >>= 1)
        s += __shfl_xor(s, off, 64);
    __shared__ float sred[4];
    if ((tid & 63) == 0) sred[tid >> 6] = s;
    __syncthreads();
    if (tid == 0)
        out[0] = ((sred[0] + sred[1]) + (sred[2] + sred[3])) * (1.0f / (float)C_);
}

extern "C" void kernel_launch(void* const* d_in, const int* in_sizes, int n_in,
                              void* d_out, int out_size, void* d_ws, size_t ws_size,
                              hipStream_t stream) {
    const float* feat   = (const float*)d_in[0];
    const float* feat_p = (const float*)d_in[1];
    const float* af     = (const float*)d_in[2];   // (2, C)
    const int*   qual   = (const int*)d_in[3];
    const int*   label  = (const int*)d_in[4];
    float* out = (float*)d_out;
    float* ws  = (float*)d_ws;                     // NBLOCKS_ floats = 16 KB

    loss_partial_kernel<<<NBLOCKS_, 64, 0, stream>>>(feat, feat_p, af, qual, label, ws);
    final_reduce_kernel<<<1, 256, 0, stream>>>(ws, out);
}